// Round 6
// baseline (2215.607 us; speedup 1.0000x reference)
//
#include <hip/hip_runtime.h>
#include <hip/hip_bf16.h>
#include <math.h>

#define LLEN 30
#define DMOD 14
#define NH 8
#define NFF 50
#define NTOP 3
#define LN_EPS 1e-5f

typedef unsigned short u16;
typedef unsigned int u32;

__device__ __forceinline__ float bflo(u32 v) {
  union { u32 u; float f; } w; w.u = v << 16; return w.f;
}
__device__ __forceinline__ float bfhi(u32 v) {
  union { u32 u; float f; } w; w.u = v & 0xFFFF0000u; return w.f;
}
__device__ __forceinline__ u16 f2bf(float f) {
  union { float f; u32 u; } w; w.f = f;
  u32 x = w.u;
  x = (x + 0x7FFFu + ((x >> 16) & 1u)) >> 16;
  return (u16)x;
}
__device__ __forceinline__ void unpack8(uint4 v, float* w) {
  w[0] = bflo(v.x); w[1] = bfhi(v.x);
  w[2] = bflo(v.y); w[3] = bfhi(v.y);
  w[4] = bflo(v.z); w[5] = bfhi(v.z);
  w[6] = bflo(v.w); w[7] = bfhi(v.w);
}

// Exact replicate-pad 25-tap moving-average removal, one contiguous 30-row.
__device__ __forceinline__ void decomp_row(float* row) {
  float xv[30];
  #pragma unroll
  for (int j = 0; j < 30; ++j) xv[j] = row[j];
  float ws = 13.f * xv[0];
  #pragma unroll
  for (int j = 1; j <= 12; ++j) ws += xv[j];
  row[0] = xv[0] - ws * (1.f / 25.f);
  #pragma unroll
  for (int l = 1; l < 30; ++l) {
    const int hi = (l + 12 > 29) ? 29 : l + 12;
    const int lo = (l - 13 < 0) ? 0 : l - 13;
    ws += xv[hi] - xv[lo];
    row[l] = xv[l] - ws * (1.f / 25.f);
  }
}

// ============================ Front-end kernel ==============================
// 128-thread blocks = 2 samples, one wave per sample, private 1260-float pool.
// Pool layout (stride-30 rows, bank=(l-2d)%32 — conflict-free for both
// lane-spans-l and per-lane row walks):
//   A[0..420):   x -> q[0..240)+mv[240..270)+tw[270..273) -> agg -> h1
//   B[420..840): embed -> LN out -> adjS[0..196)
//   C[840..1260): k -> v -> x1/s1/x2/s2 (in-place)
// LDS = 2*1260*4 + 24 = 10104 B -> 16 blocks/CU * 2 waves = 32 waves/CU.
__global__ __launch_bounds__(128, 8) void fe_kernel(
    const float* __restrict__ x,
    const float* __restrict__ W_emb, const float* __restrict__ b_emb,
    const float* __restrict__ Wq, const float* __restrict__ bq,
    const float* __restrict__ Wk, const float* __restrict__ bk,
    const float* __restrict__ Wv, const float* __restrict__ bv,
    const float* __restrict__ Wo, const float* __restrict__ bo,
    const float* __restrict__ W_ff1, const float* __restrict__ W_ff2,
    const float* __restrict__ g_norm, const float* __restrict__ b_norm,
    const float* __restrict__ W_dy, const float* __restrict__ b_dy,
    const float* __restrict__ channels,
    u16* __restrict__ f_out, int Btot)
{
  const int wid = threadIdx.x >> 6;        // sample-in-block
  const int t   = threadIdx.x & 63;        // lane
  const int b   = blockIdx.x * 2 + wid;
  const bool live = (b < Btot);

  __shared__ float pool[2 * 1260];
  __shared__ int   tdi[2][NTOP];
  float* A  = &pool[wid * 1260];
  float* Bf = A + 420;
  float* C  = A + 840;
  float* mv = A + 240;
  float* tw = A + 270;

  // ---- P0: load x transposed: A[d*30+l] = x[b][l][d] ----
  const float* xb = x + (size_t)b * (LLEN * DMOD);
  if (live) {
    for (int i = t; i < 420; i += 64) {
      const int d = i / 30, l = i - d * 30;
      A[i] = xb[l * DMOD + d];
    }
  }
  __syncthreads();

  // ---- P1: conv1d embed (k=3, zero pad 1): B[o*30+l] ----
  for (int i = t; i < 420; i += 64) {
    const int o = i / 30, l = i - o * 30;
    float acc = b_emb[o];
    #pragma unroll
    for (int dt = 0; dt < 3; ++dt) {
      const int ll = l + dt - 1;
      if ((unsigned)ll < (unsigned)LLEN) {
        #pragma unroll
        for (int c = 0; c < DMOD; ++c)
          acc += W_emb[o * (DMOD * 3) + c * 3 + dt] * A[c * 30 + ll];
      }
    }
    Bf[i] = acc;
  }
  __syncthreads();

  // ---- P2: q -> A[0..240), k -> C[0..240) (x dead) ----
  for (int i = t; i < 240; i += 64) {
    const int h = i / 30, l = i - h * 30;
    float aq = bq[h], ak = bk[h];
    #pragma unroll
    for (int d = 0; d < DMOD; ++d) {
      const float e = Bf[d * 30 + l];
      aq += Wq[d * NH + h] * e;
      ak += Wk[d * NH + h] * e;
    }
    A[i] = aq;
    C[i] = ak;
  }
  __syncthreads();

  // ---- P3: circular autocorrelation mean: lane = (tau, head-half) ----
  {
    float part = 0.f;
    const int tau = t >> 1;
    const int h0 = (t & 1) * 4;
    if (tau < LLEN) {
      for (int h = h0; h < h0 + 4; ++h) {
        float a = 0.f;
        #pragma unroll 6
        for (int s = 0; s < LLEN; ++s) {
          int sp = s + tau; if (sp >= LLEN) sp -= LLEN;
          a += A[h * 30 + sp] * C[h * 30 + s];
        }
        part += a;
      }
    }
    part += __shfl_xor(part, 1);
    if (tau < LLEN && (t & 1) == 0) mv[tau] = part * (1.f / NH);
  }
  __syncthreads();

  // ---- P4: v -> C (overwrites k); lane 0: top-3 + softmax ----
  for (int i = t; i < 240; i += 64) {
    const int h = i / 30, l = i - h * 30;
    float av = bv[h];
    #pragma unroll
    for (int d = 0; d < DMOD; ++d) av += Wv[d * NH + h] * Bf[d * 30 + l];
    C[i] = av;
  }
  if (t == 0) {
    float v1 = -1e30f, v2 = -1e30f, v3 = -1e30f; int i1 = 0, i2 = 0, i3 = 0;
    for (int i = 0; i < LLEN; ++i) {
      const float v = mv[i];
      if (v > v1)      { v3 = v2; i3 = i2; v2 = v1; i2 = i1; v1 = v; i1 = i; }
      else if (v > v2) { v3 = v2; i3 = i2; v2 = v; i2 = i; }
      else if (v > v3) { v3 = v; i3 = i; }
    }
    const float e1 = 1.f, e2 = __expf(v2 - v1), e3 = __expf(v3 - v1);
    const float inv = 1.f / (e1 + e2 + e3);
    tw[0] = e1 * inv; tw[1] = e2 * inv; tw[2] = e3 * inv;
    tdi[wid][0] = i1; tdi[wid][1] = i2; tdi[wid][2] = i3;
  }
  __syncthreads();

  // ---- P5: weighted circular gather: agg -> A[0..240) (q dead) ----
  {
    const float w0 = tw[0], w1 = tw[1], w2 = tw[2];
    const int d0 = tdi[wid][0], d1 = tdi[wid][1], d2 = tdi[wid][2];
    for (int i = t; i < 240; i += 64) {
      const int h = i / 30, l = i - h * 30;
      int ia = l + d0; if (ia >= LLEN) ia -= LLEN;
      int ib = l + d1; if (ib >= LLEN) ib -= LLEN;
      int ic = l + d2; if (ic >= LLEN) ic -= LLEN;
      A[i] = w0 * C[h * 30 + ia] + w1 * C[h * 30 + ib] + w2 * C[h * 30 + ic];
    }
  }
  __syncthreads();

  // ---- P6: out-proj + residual: x1 -> C (v dead) ----
  for (int i = t; i < 420; i += 64) {
    const int d = i / 30, l = i - d * 30;
    float acc = bo[d];
    #pragma unroll
    for (int h = 0; h < NH; ++h) acc += A[h * 30 + l] * Wo[h * DMOD + d];
    C[i] = Bf[i] + acc;
  }
  __syncthreads();

  // ---- P7: series_decomp #1: C = s1 ----
  if (t < DMOD) decomp_row(&C[t * 30]);
  __syncthreads();

  // ---- P8: FFN fused (lane = (l, f-half)); x2 = s1 + gelu(s1@W1)@W2 -> C ----
  {
    const int l = t >> 1;
    const int half = t & 1;
    if (l < LLEN) {
      float sr[DMOD];
      #pragma unroll
      for (int d = 0; d < DMOD; ++d) sr[d] = C[d * 30 + l];
      float y[DMOD];
      #pragma unroll
      for (int d = 0; d < DMOD; ++d) y[d] = 0.f;
      const int f0 = half * 25;
      for (int f = f0; f < f0 + 25; ++f) {
        float a = 0.f;
        #pragma unroll
        for (int d = 0; d < DMOD; ++d) a += sr[d] * W_ff1[d * NFF + f];
        const float g = 0.5f * a * (1.f + erff(a * 0.70710678118654752f));
        #pragma unroll
        for (int d = 0; d < DMOD; ++d) y[d] += g * W_ff2[f * DMOD + d];
      }
      #pragma unroll
      for (int d = 0; d < DMOD; ++d) y[d] += __shfl_xor(y[d], 1);
      if (half == 0) {
        #pragma unroll
        for (int d = 0; d < DMOD; ++d) C[d * 30 + l] = sr[d] + y[d];
      }
    }
  }
  __syncthreads();

  // ---- P9: series_decomp #2: C = s2 ----
  if (t < DMOD) decomp_row(&C[t * 30]);
  __syncthreads();

  // ---- P10: LayerNorm over D -> B (embed dead) ----
  if (t < LLEN) {
    const int l = t;
    float m = 0.f;
    #pragma unroll
    for (int d = 0; d < DMOD; ++d) m += C[d * 30 + l];
    m *= (1.f / DMOD);
    float v2 = 0.f;
    #pragma unroll
    for (int d = 0; d < DMOD; ++d) { const float z = C[d * 30 + l] - m; v2 += z * z; }
    v2 *= (1.f / DMOD);
    const float inv = rsqrtf(v2 + LN_EPS);
    #pragma unroll
    for (int d = 0; d < DMOD; ++d)
      Bf[d * 30 + l] = (C[d * 30 + l] - m) * inv * g_norm[d] + b_norm[d];
  }
  __syncthreads();

  // ---- P11: DyConv time-linear: h1 -> A (agg/mv/tw dead) ----
  for (int i = t; i < 420; i += 64) {
    const int d = i / 30, l = i - d * 30;
    float acc = b_dy[l];
    #pragma unroll 6
    for (int lp = 0; lp < LLEN; ++lp) acc += Bf[d * 30 + lp] * W_dy[lp * LLEN + l];
    A[i] = acc;
  }
  __syncthreads();

  // ---- P12: adjacency softmax -> B[0..196) (LN out dead) ----
  if (t < DMOD) {
    float row[DMOD];
    float m = -1e30f;
    #pragma unroll
    for (int j = 0; j < DMOD; ++j) { row[j] = channels[t * DMOD + j]; m = fmaxf(m, row[j]); }
    float s = 0.f;
    #pragma unroll
    for (int j = 0; j < DMOD; ++j) { row[j] = __expf(row[j] - m); s += row[j]; }
    const float inv = 1.f / s;
    #pragma unroll
    for (int j = 0; j < DMOD; ++j) Bf[t * DMOD + j] = row[j] * inv;
  }
  __syncthreads();

  // ---- P13: dy = relu(adj @ h1); write f (bf16) ----
  if (live) {
    for (int i = t; i < 420; i += 64) {
      const int d2 = i / 30, l = i - d2 * 30;
      float acc = 0.f;
      #pragma unroll
      for (int j = 0; j < DMOD; ++j) acc += Bf[d2 * DMOD + j] * A[j * 30 + l];
      f_out[(size_t)b * 420 + i] = f2bf(fmaxf(acc, 0.f));
    }
  }
}

// ============================ MLP head kernel ===============================
#define SB 32
#define TI 32

__global__ __launch_bounds__(256, 2) void head_kernel(
    const u16* __restrict__ fin,
    const float* __restrict__ W1, const float* __restrict__ b1,
    const float* __restrict__ W2, const float* __restrict__ b2,
    const float* __restrict__ Wres, const float* __restrict__ bres,
    const float* __restrict__ g_ln, const float* __restrict__ b_ln,
    const float* __restrict__ W3, const float* __restrict__ b3,
    float* __restrict__ out, int Btot)
{
  const int t = threadIdx.x;
  const int b0 = blockIdx.x * SB;

  __shared__ __align__(16) u32 fT32[420 * 18];  // f, 2 bf16 samples / u32
  __shared__ __align__(16) u32 w1t[TI * 128];   // W1 tile, 2 bf16 cols / u32
  __shared__ __align__(16) u32 h32[SB * 132];   // h rows, 2 bf16 / u32

  for (int idx = t; idx < (SB / 2) * 420; idx += 256) {
    int sp = idx / 420, i = idx - sp * 420;
    int g0 = b0 + 2 * sp, g1 = g0 + 1;
    u32 lo = (g0 < Btot) ? (u32)fin[(size_t)g0 * 420 + i] : 0u;
    u32 hi = (g1 < Btot) ? (u32)fin[(size_t)g1 * 420 + i] : 0u;
    fT32[i * 18 + sp] = lo | (hi << 16);
  }

  const int jg = t >> 3;
  const int sg = t & 7;
  const int j0 = jg * 8;

  float acc[4][8];
  #pragma unroll
  for (int u = 0; u < 4; ++u)
    #pragma unroll
    for (int e = 0; e < 8; ++e) acc[u][e] = 0.f;

  for (int i0 = 0; i0 < 420; i0 += TI) {
    const int ti = (420 - i0) < TI ? (420 - i0) : TI;
    __syncthreads();
    for (int idx = t; idx < ti * 128; idx += 256) {
      int r = idx >> 7, cp = idx & 127;
      float2 wf = *((const float2*)&W1[(size_t)(i0 + r) * 256 + 2 * cp]);
      w1t[idx] = (u32)f2bf(wf.x) | ((u32)f2bf(wf.y) << 16);
    }
    __syncthreads();
    for (int ii = 0; ii < ti; ++ii) {
      uint2 fv = *((const uint2*)&fT32[(i0 + ii) * 18 + sg * 2]);
      float f0 = bflo(fv.x), f1 = bfhi(fv.x), f2v = bflo(fv.y), f3 = bfhi(fv.y);
      uint4 wv = *((const uint4*)&w1t[ii * 128 + jg * 4]);
      float w[8];
      unpack8(wv, w);
      #pragma unroll
      for (int e = 0; e < 8; ++e) {
        acc[0][e] += f0 * w[e];
        acc[1][e] += f1 * w[e];
        acc[2][e] += f2v * w[e];
        acc[3][e] += f3 * w[e];
      }
    }
  }
  __syncthreads();

  #pragma unroll
  for (int u = 0; u < 4; ++u) {
    uint4 pk;
    u32 p[4];
    #pragma unroll
    for (int q = 0; q < 4; ++q) {
      float a = fmaxf(acc[u][2 * q]     + b1[j0 + 2 * q], 0.f);
      float c = fmaxf(acc[u][2 * q + 1] + b1[j0 + 2 * q + 1], 0.f);
      p[q] = (u32)f2bf(a) | ((u32)f2bf(c) << 16);
    }
    pk.x = p[0]; pk.y = p[1]; pk.z = p[2]; pk.w = p[3];
    *((uint4*)&h32[(sg * 4 + u) * 132 + jg * 4]) = pk;
  }
  __syncthreads();

  const int s2 = t >> 3;
  const int c8 = (t & 7) * 8;
  float a2[8];
  #pragma unroll
  for (int e = 0; e < 8; ++e) a2[e] = b2[c8 + e] + bres[c8 + e];

  for (int i2 = 0; i2 < 128; ++i2) {
    u32 hp = h32[s2 * 132 + i2];
    float h0 = bflo(hp), h1v = bfhi(hp);
    float4 wa0 = *((const float4*)&W2[(size_t)(2 * i2) * 64 + c8]);
    float4 wa1 = *((const float4*)&W2[(size_t)(2 * i2) * 64 + c8 + 4]);
    float4 wb0 = *((const float4*)&W2[(size_t)(2 * i2 + 1) * 64 + c8]);
    float4 wb1 = *((const float4*)&W2[(size_t)(2 * i2 + 1) * 64 + c8 + 4]);
    a2[0] += h0 * wa0.x + h1v * wb0.x;
    a2[1] += h0 * wa0.y + h1v * wb0.y;
    a2[2] += h0 * wa0.z + h1v * wb0.z;
    a2[3] += h0 * wa0.w + h1v * wb0.w;
    a2[4] += h0 * wa1.x + h1v * wb1.x;
    a2[5] += h0 * wa1.y + h1v * wb1.y;
    a2[6] += h0 * wa1.z + h1v * wb1.z;
    a2[7] += h0 * wa1.w + h1v * wb1.w;
  }
  const int spair = s2 >> 1;
  const int shalf = s2 & 1;
  for (int i = 0; i < 420; ++i) {
    u32 fp2 = fT32[i * 18 + spair];
    float fv = shalf ? bfhi(fp2) : bflo(fp2);
    float4 wr0 = *((const float4*)&Wres[(size_t)i * 64 + c8]);
    float4 wr1 = *((const float4*)&Wres[(size_t)i * 64 + c8 + 4]);
    a2[0] += fv * wr0.x; a2[1] += fv * wr0.y;
    a2[2] += fv * wr0.z; a2[3] += fv * wr0.w;
    a2[4] += fv * wr1.x; a2[5] += fv * wr1.y;
    a2[6] += fv * wr1.z; a2[7] += fv * wr1.w;
  }

  float s1 = 0.f, sq = 0.f;
  #pragma unroll
  for (int e = 0; e < 8; ++e) { s1 += a2[e]; sq += a2[e] * a2[e]; }
  s1 += __shfl_xor(s1, 1); s1 += __shfl_xor(s1, 2); s1 += __shfl_xor(s1, 4);
  sq += __shfl_xor(sq, 1); sq += __shfl_xor(sq, 2); sq += __shfl_xor(sq, 4);
  float mean = s1 * (1.f / 64.f);
  float var = sq * (1.f / 64.f) - mean * mean;
  float inv = rsqrtf(var + LN_EPS);
  float pr = 0.f;
  #pragma unroll
  for (int e = 0; e < 8; ++e) {
    float n = (a2[e] - mean) * inv * g_ln[c8 + e] + b_ln[c8 + e];
    pr += n * W3[c8 + e];
  }
  pr += __shfl_xor(pr, 1); pr += __shfl_xor(pr, 2); pr += __shfl_xor(pr, 4);
  if ((t & 7) == 0 && (b0 + s2) < Btot) out[b0 + s2] = pr + b3[0];
}

extern "C" void kernel_launch(void* const* d_in, const int* in_sizes, int n_in,
                              void* d_out, int out_size, void* d_ws, size_t ws_size,
                              hipStream_t stream) {
  const float* x        = (const float*)d_in[0];
  const float* W_emb    = (const float*)d_in[1];
  const float* b_emb    = (const float*)d_in[2];
  const float* Wq       = (const float*)d_in[3];
  const float* bq       = (const float*)d_in[4];
  const float* Wk       = (const float*)d_in[5];
  const float* bk       = (const float*)d_in[6];
  const float* Wv       = (const float*)d_in[7];
  const float* bv       = (const float*)d_in[8];
  const float* Wo       = (const float*)d_in[9];
  const float* bo       = (const float*)d_in[10];
  const float* W_ff1    = (const float*)d_in[11];
  const float* W_ff2    = (const float*)d_in[12];
  const float* g_norm   = (const float*)d_in[13];
  const float* b_norm   = (const float*)d_in[14];
  const float* W_dy     = (const float*)d_in[15];
  const float* b_dy     = (const float*)d_in[16];
  const float* channels = (const float*)d_in[17];
  const float* W1       = (const float*)d_in[18];
  const float* b1       = (const float*)d_in[19];
  const float* W2       = (const float*)d_in[20];
  const float* b2       = (const float*)d_in[21];
  const float* Wres     = (const float*)d_in[22];
  const float* bres     = (const float*)d_in[23];
  const float* g_ln     = (const float*)d_in[24];
  const float* b_ln     = (const float*)d_in[25];
  const float* W3       = (const float*)d_in[26];
  const float* b3       = (const float*)d_in[27];

  const int B = in_sizes[0] / (LLEN * DMOD);
  u16* fbuf = (u16*)d_ws;   // B*420 bf16 ≈ 55 MB scratch

  const int nb_fe = (B + 1) / 2;
  fe_kernel<<<nb_fe, 128, 0, stream>>>(x, W_emb, b_emb, Wq, bq, Wk, bk, Wv, bv, Wo, bo,
                                       W_ff1, W_ff2, g_norm, b_norm, W_dy, b_dy, channels,
                                       fbuf, B);

  const int nb = (B + SB - 1) / SB;
  head_kernel<<<nb, 256, 0, stream>>>(fbuf, W1, b1, W2, b2, Wres, bres,
                                      g_ln, b_ln, W3, b3, (float*)d_out, B);
}

// Round 7
// 1063.755 us; speedup vs baseline: 2.0828x; 2.0828x over previous
//
#include <hip/hip_runtime.h>
#include <hip/hip_bf16.h>
#include <math.h>

#define LLEN 30
#define DMOD 14
#define NH 8
#define NFF 50
#define LN_EPS 1e-5f

typedef unsigned short u16;
typedef unsigned int u32;

__device__ __forceinline__ float bflo(u32 v) {
  union { u32 u; float f; } w; w.u = v << 16; return w.f;
}
__device__ __forceinline__ float bfhi(u32 v) {
  union { u32 u; float f; } w; w.u = v & 0xFFFF0000u; return w.f;
}
__device__ __forceinline__ u16 f2bf(float f) {
  union { float f; u32 u; } w; w.f = f;
  u32 x = w.u;
  x = (x + 0x7FFFu + ((x >> 16) & 1u)) >> 16;
  return (u16)x;
}
__device__ __forceinline__ void unpack8(uint4 v, float* w) {
  w[0] = bflo(v.x); w[1] = bfhi(v.x);
  w[2] = bflo(v.y); w[3] = bfhi(v.y);
  w[4] = bflo(v.z); w[5] = bfhi(v.z);
  w[6] = bflo(v.w); w[7] = bfhi(v.w);
}

// Exact replicate-pad 25-tap MA removal on one contiguous 30-float LDS row.
// Reads/writes via b64; keeps originals in regs so in-place write is safe.
__device__ __forceinline__ void decomp_row_lds(float* row) {
  float xv[30];
  const float2* r2 = (const float2*)row;
  #pragma unroll
  for (int j = 0; j < 15; ++j) { float2 w = r2[j]; xv[2*j] = w.x; xv[2*j+1] = w.y; }
  float2* w2 = (float2*)row;
  float ws = 13.f * xv[0];
  #pragma unroll
  for (int j = 1; j <= 12; ++j) ws += xv[j];
  float rprev = xv[0] - ws * (1.f / 25.f);
  #pragma unroll
  for (int jj = 1; jj < 30; ++jj) {
    const int hi = (jj + 12 > 29) ? 29 : jj + 12;
    const int lo = (jj - 13 < 0) ? 0 : jj - 13;
    ws += xv[hi] - xv[lo];
    const float r = xv[jj] - ws * (1.f / 25.f);
    if (jj & 1) { w2[jj >> 1] = make_float2(rprev, r); } else { rprev = r; }
  }
}

// ============================ Front-end kernel ==============================
// lane = timestep l; one wave = 2 samples (lanes 0-29 / 32-61).
// Activations in registers; weights via wave-uniform scalar loads; LDS only
// for cross-lane phases (autocorr q/k, decomp transpose, DyConv u-rows).
__global__ __launch_bounds__(64, 6) void fe_kernel(
    const float* __restrict__ x,
    const float* __restrict__ W_emb, const float* __restrict__ b_emb,
    const float* __restrict__ Wq, const float* __restrict__ bq,
    const float* __restrict__ Wk, const float* __restrict__ bk,
    const float* __restrict__ Wv, const float* __restrict__ bv,
    const float* __restrict__ Wo, const float* __restrict__ bo,
    const float* __restrict__ W_ff1, const float* __restrict__ W_ff2,
    const float* __restrict__ g_norm, const float* __restrict__ b_norm,
    const float* __restrict__ W_dy, const float* __restrict__ b_dy,
    const float* __restrict__ channels,
    u16* __restrict__ f_out, int Btot)
{
  const int t    = threadIdx.x;
  const int half = t >> 5;
  const int l    = t & 31;
  const int base = half << 5;
  const bool act = (l < LLEN);
  const int b    = blockIdx.x * 2 + half;
  const bool live = act && (b < Btot);

  // Per-wave LDS. pool reused across phases:
  //   QK:  q rows [l*10..l*10+7], k rows [300+l*10..]   (b64, stride10: 2-way)
  //   T :  [d*30 + l] transpose buffer for decomp        (b64 rows, 8B aligned)
  //   U :  [l*16 + i] DyConv u-rows                      (64B aligned, b128)
  __shared__ float pool[2][600];
  __shared__ float adjLDS[DMOD][16];
  __shared__ float MV[2][32];
  __shared__ float TW[2][4];
  __shared__ int   TD[2][4];

  // ---- P0: load x (lane l holds x[b][l][0..13]); lanes t<14 compute adj ----
  float xr[DMOD];
  if (live) {
    const float2* xp2 = (const float2*)(x + (size_t)b * 420 + l * DMOD);
    #pragma unroll
    for (int j = 0; j < 7; ++j) { float2 v = xp2[j]; xr[2*j] = v.x; xr[2*j+1] = v.y; }
  } else {
    #pragma unroll
    for (int d = 0; d < DMOD; ++d) xr[d] = 0.f;
  }
  if (t < DMOD) {
    float row[DMOD]; float m = -1e30f;
    #pragma unroll
    for (int j = 0; j < DMOD; ++j) { row[j] = channels[t * DMOD + j]; m = fmaxf(m, row[j]); }
    float s = 0.f;
    #pragma unroll
    for (int j = 0; j < DMOD; ++j) { row[j] = __expf(row[j] - m); s += row[j]; }
    const float inv = 1.f / s;
    #pragma unroll
    for (int j = 0; j < DMOD; ++j) adjLDS[t][j] = row[j] * inv;
  }

  // ---- P1: conv1d embed (k=3, zero pad): xe[o] in regs; neighbors via shfl ----
  float xe[DMOD];
  #pragma unroll
  for (int o = 0; o < DMOD; ++o) xe[o] = b_emb[o];
  #pragma unroll
  for (int c = 0; c < DMOD; ++c) {
    float xm = __shfl(xr[c], t - 1);
    float xp = __shfl(xr[c], t + 1);
    xm = (l == 0) ? 0.f : xm;
    xp = (l >= LLEN - 1) ? 0.f : xp;
    const float xc = xr[c];
    #pragma unroll
    for (int o = 0; o < DMOD; ++o) {
      const float* wp = W_emb + o * (DMOD * 3) + c * 3;
      xe[o] += wp[0] * xm + wp[1] * xc + wp[2] * xp;
    }
  }

  // ---- P2: q,k,v in regs (SGPR weights) ----
  float q[NH], k[NH], v[NH];
  #pragma unroll
  for (int h = 0; h < NH; ++h) { q[h] = bq[h]; k[h] = bk[h]; v[h] = bv[h]; }
  #pragma unroll
  for (int d = 0; d < DMOD; ++d) {
    const float e = xe[d];
    #pragma unroll
    for (int h = 0; h < NH; ++h) {
      q[h] += Wq[d * NH + h] * e;
      k[h] += Wk[d * NH + h] * e;
      v[h] += Wv[d * NH + h] * e;
    }
  }

  // ---- P3: autocorr via LDS q/k rows; lane tau=l computes corr ----
  if (act) {
    float2* qr = (float2*)&pool[half][l * 10];
    qr[0] = make_float2(q[0], q[1]); qr[1] = make_float2(q[2], q[3]);
    qr[2] = make_float2(q[4], q[5]); qr[3] = make_float2(q[6], q[7]);
    float2* kr = (float2*)&pool[half][300 + l * 10];
    kr[0] = make_float2(k[0], k[1]); kr[1] = make_float2(k[2], k[3]);
    kr[2] = make_float2(k[4], k[5]); kr[3] = make_float2(k[6], k[7]);
  }
  __syncthreads();
  if (act) {
    float acc = 0.f;
    #pragma unroll 5
    for (int s = 0; s < LLEN; ++s) {
      int rq = l + s; if (rq >= LLEN) rq -= LLEN;
      const float2* qa = (const float2*)&pool[half][rq * 10];
      const float2* ka = (const float2*)&pool[half][300 + s * 10];
      float2 a0 = qa[0], a1 = qa[1], a2 = qa[2], a3 = qa[3];
      float2 b0 = ka[0], b1 = ka[1], b2 = ka[2], b3 = ka[3];
      acc += a0.x * b0.x + a0.y * b0.y + a1.x * b1.x + a1.y * b1.y
           + a2.x * b2.x + a2.y * b2.y + a3.x * b3.x + a3.y * b3.y;
    }
    MV[half][l] = acc * (1.f / NH);
  }
  __syncthreads();

  // ---- P4: top-3 + softmax (lane 0 of each half; strict > = lax.top_k) ----
  if (l == 0) {
    float v1 = -1e30f, v2 = -1e30f, v3 = -1e30f; int i1 = 0, i2 = 0, i3 = 0;
    for (int i = 0; i < LLEN; ++i) {
      const float vv = MV[half][i];
      if (vv > v1)      { v3 = v2; i3 = i2; v2 = v1; i2 = i1; v1 = vv; i1 = i; }
      else if (vv > v2) { v3 = v2; i3 = i2; v2 = vv; i2 = i; }
      else if (vv > v3) { v3 = vv; i3 = i; }
    }
    const float e2 = __expf(v2 - v1), e3 = __expf(v3 - v1);
    const float inv = 1.f / (1.f + e2 + e3);
    TW[half][0] = inv; TW[half][1] = e2 * inv; TW[half][2] = e3 * inv;
    TD[half][0] = i1; TD[half][1] = i2; TD[half][2] = i3;
  }
  __syncthreads();

  // ---- P5: weighted circular gather via shfl of v ----
  float agg[NH];
  #pragma unroll
  for (int h = 0; h < NH; ++h) agg[h] = 0.f;
  #pragma unroll
  for (int kk = 0; kk < 3; ++kk) {
    const float w = TW[half][kk];
    const int dd = TD[half][kk];
    int sidx = l + dd; if (sidx >= LLEN) sidx -= LLEN;
    const int src = base + sidx;
    #pragma unroll
    for (int h = 0; h < NH; ++h) agg[h] += w * __shfl(v[h], src);
  }

  // ---- P6: out-proj + residual: x1 in xe ----
  #pragma unroll
  for (int d = 0; d < DMOD; ++d) {
    float a = bo[d];
    #pragma unroll
    for (int h = 0; h < NH; ++h) a += agg[h] * Wo[h * DMOD + d];
    xe[d] += a;
  }
  __syncthreads();

  // ---- P7: decomp #1 via LDS transpose ----
  if (act) {
    #pragma unroll
    for (int d = 0; d < DMOD; ++d) pool[half][d * LLEN + l] = xe[d];
  }
  __syncthreads();
  if (l < DMOD) decomp_row_lds(&pool[half][l * LLEN]);
  __syncthreads();
  float s1[DMOD];
  if (act) {
    #pragma unroll
    for (int d = 0; d < DMOD; ++d) s1[d] = pool[half][d * LLEN + l];
  } else {
    #pragma unroll
    for (int d = 0; d < DMOD; ++d) s1[d] = 0.f;
  }
  __syncthreads();

  // ---- P8: FFN fully in regs: x2 = s1 + gelu(s1@W_ff1)@W_ff2 ----
  float y[DMOD];
  #pragma unroll
  for (int d = 0; d < DMOD; ++d) y[d] = 0.f;
  for (int f = 0; f < NFF; ++f) {
    float a = 0.f;
    #pragma unroll
    for (int d = 0; d < DMOD; ++d) a += s1[d] * W_ff1[d * NFF + f];
    const float g = 0.5f * a * (1.f + erff(a * 0.70710678118654752f));
    #pragma unroll
    for (int d = 0; d < DMOD; ++d) y[d] += g * W_ff2[f * DMOD + d];
  }

  // ---- P9: decomp #2 via LDS transpose ----
  if (act) {
    #pragma unroll
    for (int d = 0; d < DMOD; ++d) pool[half][d * LLEN + l] = s1[d] + y[d];
  }
  __syncthreads();
  if (l < DMOD) decomp_row_lds(&pool[half][l * LLEN]);
  __syncthreads();

  // ---- P10: LayerNorm over D (fully local) ----
  float ln[DMOD];
  if (act) {
    float s2v[DMOD];
    #pragma unroll
    for (int d = 0; d < DMOD; ++d) s2v[d] = pool[half][d * LLEN + l];
    float m = 0.f;
    #pragma unroll
    for (int d = 0; d < DMOD; ++d) m += s2v[d];
    m *= (1.f / DMOD);
    float va = 0.f;
    #pragma unroll
    for (int d = 0; d < DMOD; ++d) { const float z = s2v[d] - m; va += z * z; }
    va *= (1.f / DMOD);
    const float inv = rsqrtf(va + LN_EPS);
    #pragma unroll
    for (int d = 0; d < DMOD; ++d) ln[d] = (s2v[d] - m) * inv * g_norm[d] + b_norm[d];
  } else {
    #pragma unroll
    for (int d = 0; d < DMOD; ++d) ln[d] = 0.f;
  }
  __syncthreads();

  // ---- P11: u = adj @ ln (adj via b128 LDS broadcast); write u-rows ----
  float u[DMOD];
  #pragma unroll
  for (int i = 0; i < DMOD; ++i) {
    const float4* ar = (const float4*)&adjLDS[i][0];
    const float4 c0 = ar[0], c1 = ar[1], c2 = ar[2];
    const float2 c3 = ((const float2*)ar)[6];
    u[i] = c0.x * ln[0] + c0.y * ln[1] + c0.z * ln[2] + c0.w * ln[3]
         + c1.x * ln[4] + c1.y * ln[5] + c1.z * ln[6] + c1.w * ln[7]
         + c2.x * ln[8] + c2.y * ln[9] + c2.z * ln[10] + c2.w * ln[11]
         + c3.x * ln[12] + c3.y * ln[13];
  }
  if (act) {
    float4* ur = (float4*)&pool[half][l * 16];
    ur[0] = make_float4(u[0], u[1], u[2], u[3]);
    ur[1] = make_float4(u[4], u[5], u[6], u[7]);
    ur[2] = make_float4(u[8], u[9], u[10], u[11]);
    ((float2*)ur)[6] = make_float2(u[12], u[13]);
  }
  __syncthreads();

  // ---- P12: dy[i][l] = relu(sum_lp u[i][lp]*W_dy[lp][l] + b_dy[l]); write f.
  // (adj rows sum to 1, so adj@(b_dy bcast) == b_dy — folded exactly.)
  if (live) {
    float acc[DMOD];
    #pragma unroll
    for (int i = 0; i < DMOD; ++i) acc[i] = 0.f;
    #pragma unroll 5
    for (int lp = 0; lp < LLEN; ++lp) {
      const float wd = W_dy[lp * LLEN + l];
      const float4* ur = (const float4*)&pool[half][lp * 16];
      const float4 a0 = ur[0], a1 = ur[1], a2 = ur[2];
      const float2 a3 = ((const float2*)ur)[6];
      acc[0] += a0.x * wd;  acc[1] += a0.y * wd;  acc[2]  += a0.z * wd;  acc[3]  += a0.w * wd;
      acc[4] += a1.x * wd;  acc[5] += a1.y * wd;  acc[6]  += a1.z * wd;  acc[7]  += a1.w * wd;
      acc[8] += a2.x * wd;  acc[9] += a2.y * wd;  acc[10] += a2.z * wd;  acc[11] += a2.w * wd;
      acc[12] += a3.x * wd; acc[13] += a3.y * wd;
    }
    const float bd = b_dy[l];
    u16* fo = f_out + (size_t)b * 420 + l;
    #pragma unroll
    for (int i = 0; i < DMOD; ++i)
      fo[i * LLEN] = f2bf(fmaxf(acc[i] + bd, 0.f));
  }
}

// ============================ MLP head kernel ===============================
#define SB 32
#define TI 32

__global__ __launch_bounds__(256, 2) void head_kernel(
    const u16* __restrict__ fin,
    const float* __restrict__ W1, const float* __restrict__ b1,
    const float* __restrict__ W2, const float* __restrict__ b2,
    const float* __restrict__ Wres, const float* __restrict__ bres,
    const float* __restrict__ g_ln, const float* __restrict__ b_ln,
    const float* __restrict__ W3, const float* __restrict__ b3,
    float* __restrict__ out, int Btot)
{
  const int t = threadIdx.x;
  const int b0 = blockIdx.x * SB;

  __shared__ __align__(16) u32 fT32[420 * 18];  // f, 2 bf16 samples / u32
  __shared__ __align__(16) u32 w1t[TI * 128];   // W1 tile, 2 bf16 cols / u32
  __shared__ __align__(16) u32 h32[SB * 132];   // h rows, 2 bf16 / u32

  for (int idx = t; idx < (SB / 2) * 420; idx += 256) {
    int sp = idx / 420, i = idx - sp * 420;
    int g0 = b0 + 2 * sp, g1 = g0 + 1;
    u32 lo = (g0 < Btot) ? (u32)fin[(size_t)g0 * 420 + i] : 0u;
    u32 hi = (g1 < Btot) ? (u32)fin[(size_t)g1 * 420 + i] : 0u;
    fT32[i * 18 + sp] = lo | (hi << 16);
  }

  const int jg = t >> 3;
  const int sg = t & 7;
  const int j0 = jg * 8;

  float acc[4][8];
  #pragma unroll
  for (int u = 0; u < 4; ++u)
    #pragma unroll
    for (int e = 0; e < 8; ++e) acc[u][e] = 0.f;

  for (int i0 = 0; i0 < 420; i0 += TI) {
    const int ti = (420 - i0) < TI ? (420 - i0) : TI;
    __syncthreads();
    for (int idx = t; idx < ti * 128; idx += 256) {
      int r = idx >> 7, cp = idx & 127;
      float2 wf = *((const float2*)&W1[(size_t)(i0 + r) * 256 + 2 * cp]);
      w1t[idx] = (u32)f2bf(wf.x) | ((u32)f2bf(wf.y) << 16);
    }
    __syncthreads();
    for (int ii = 0; ii < ti; ++ii) {
      uint2 fv = *((const uint2*)&fT32[(i0 + ii) * 18 + sg * 2]);
      float f0 = bflo(fv.x), f1 = bfhi(fv.x), f2v = bflo(fv.y), f3 = bfhi(fv.y);
      uint4 wv = *((const uint4*)&w1t[ii * 128 + jg * 4]);
      float w[8];
      unpack8(wv, w);
      #pragma unroll
      for (int e = 0; e < 8; ++e) {
        acc[0][e] += f0 * w[e];
        acc[1][e] += f1 * w[e];
        acc[2][e] += f2v * w[e];
        acc[3][e] += f3 * w[e];
      }
    }
  }
  __syncthreads();

  #pragma unroll
  for (int u = 0; u < 4; ++u) {
    uint4 pk;
    u32 p[4];
    #pragma unroll
    for (int q = 0; q < 4; ++q) {
      float a = fmaxf(acc[u][2 * q]     + b1[j0 + 2 * q], 0.f);
      float c = fmaxf(acc[u][2 * q + 1] + b1[j0 + 2 * q + 1], 0.f);
      p[q] = (u32)f2bf(a) | ((u32)f2bf(c) << 16);
    }
    pk.x = p[0]; pk.y = p[1]; pk.z = p[2]; pk.w = p[3];
    *((uint4*)&h32[(sg * 4 + u) * 132 + jg * 4]) = pk;
  }
  __syncthreads();

  const int s2 = t >> 3;
  const int c8 = (t & 7) * 8;
  float a2[8];
  #pragma unroll
  for (int e = 0; e < 8; ++e) a2[e] = b2[c8 + e] + bres[c8 + e];

  for (int i2 = 0; i2 < 128; ++i2) {
    u32 hp = h32[s2 * 132 + i2];
    float h0 = bflo(hp), h1v = bfhi(hp);
    float4 wa0 = *((const float4*)&W2[(size_t)(2 * i2) * 64 + c8]);
    float4 wa1 = *((const float4*)&W2[(size_t)(2 * i2) * 64 + c8 + 4]);
    float4 wb0 = *((const float4*)&W2[(size_t)(2 * i2 + 1) * 64 + c8]);
    float4 wb1 = *((const float4*)&W2[(size_t)(2 * i2 + 1) * 64 + c8 + 4]);
    a2[0] += h0 * wa0.x + h1v * wb0.x;
    a2[1] += h0 * wa0.y + h1v * wb0.y;
    a2[2] += h0 * wa0.z + h1v * wb0.z;
    a2[3] += h0 * wa0.w + h1v * wb0.w;
    a2[4] += h0 * wa1.x + h1v * wb1.x;
    a2[5] += h0 * wa1.y + h1v * wb1.y;
    a2[6] += h0 * wa1.z + h1v * wb1.z;
    a2[7] += h0 * wa1.w + h1v * wb1.w;
  }
  const int spair = s2 >> 1;
  const int shalf = s2 & 1;
  for (int i = 0; i < 420; ++i) {
    u32 fp2 = fT32[i * 18 + spair];
    float fv = shalf ? bfhi(fp2) : bflo(fp2);
    float4 wr0 = *((const float4*)&Wres[(size_t)i * 64 + c8]);
    float4 wr1 = *((const float4*)&Wres[(size_t)i * 64 + c8 + 4]);
    a2[0] += fv * wr0.x; a2[1] += fv * wr0.y;
    a2[2] += fv * wr0.z; a2[3] += fv * wr0.w;
    a2[4] += fv * wr1.x; a2[5] += fv * wr1.y;
    a2[6] += fv * wr1.z; a2[7] += fv * wr1.w;
  }

  float s1 = 0.f, sq = 0.f;
  #pragma unroll
  for (int e = 0; e < 8; ++e) { s1 += a2[e]; sq += a2[e] * a2[e]; }
  s1 += __shfl_xor(s1, 1); s1 += __shfl_xor(s1, 2); s1 += __shfl_xor(s1, 4);
  sq += __shfl_xor(sq, 1); sq += __shfl_xor(sq, 2); sq += __shfl_xor(sq, 4);
  float mean = s1 * (1.f / 64.f);
  float var = sq * (1.f / 64.f) - mean * mean;
  float inv = rsqrtf(var + LN_EPS);
  float pr = 0.f;
  #pragma unroll
  for (int e = 0; e < 8; ++e) {
    float n = (a2[e] - mean) * inv * g_ln[c8 + e] + b_ln[c8 + e];
    pr += n * W3[c8 + e];
  }
  pr += __shfl_xor(pr, 1); pr += __shfl_xor(pr, 2); pr += __shfl_xor(pr, 4);
  if ((t & 7) == 0 && (b0 + s2) < Btot) out[b0 + s2] = pr + b3[0];
}

extern "C" void kernel_launch(void* const* d_in, const int* in_sizes, int n_in,
                              void* d_out, int out_size, void* d_ws, size_t ws_size,
                              hipStream_t stream) {
  const float* x        = (const float*)d_in[0];
  const float* W_emb    = (const float*)d_in[1];
  const float* b_emb    = (const float*)d_in[2];
  const float* Wq       = (const float*)d_in[3];
  const float* bq       = (const float*)d_in[4];
  const float* Wk       = (const float*)d_in[5];
  const float* bk       = (const float*)d_in[6];
  const float* Wv       = (const float*)d_in[7];
  const float* bv       = (const float*)d_in[8];
  const float* Wo       = (const float*)d_in[9];
  const float* bo       = (const float*)d_in[10];
  const float* W_ff1    = (const float*)d_in[11];
  const float* W_ff2    = (const float*)d_in[12];
  const float* g_norm   = (const float*)d_in[13];
  const float* b_norm   = (const float*)d_in[14];
  const float* W_dy     = (const float*)d_in[15];
  const float* b_dy     = (const float*)d_in[16];
  const float* channels = (const float*)d_in[17];
  const float* W1       = (const float*)d_in[18];
  const float* b1       = (const float*)d_in[19];
  const float* W2       = (const float*)d_in[20];
  const float* b2       = (const float*)d_in[21];
  const float* Wres     = (const float*)d_in[22];
  const float* bres     = (const float*)d_in[23];
  const float* g_ln     = (const float*)d_in[24];
  const float* b_ln     = (const float*)d_in[25];
  const float* W3       = (const float*)d_in[26];
  const float* b3       = (const float*)d_in[27];

  const int B = in_sizes[0] / (LLEN * DMOD);
  u16* fbuf = (u16*)d_ws;   // B*420 bf16 ≈ 55 MB scratch

  const int nb_fe = (B + 1) / 2;
  fe_kernel<<<nb_fe, 64, 0, stream>>>(x, W_emb, b_emb, Wq, bq, Wk, bk, Wv, bv, Wo, bo,
                                      W_ff1, W_ff2, g_norm, b_norm, W_dy, b_dy, channels,
                                      fbuf, B);

  const int nb = (B + SB - 1) / SB;
  head_kernel<<<nb, 256, 0, stream>>>(fbuf, W1, b1, W2, b2, Wres, bres,
                                      g_ln, b_ln, W3, b3, (float*)d_out, B);
}